// Round 9
// baseline (215.638 us; speedup 1.0000x reference)
//
#include <hip/hip_runtime.h>
#include <stdint.h>

#define NN 100000            // nodes
#define NE 800000            // edges
#define ND 256               // dim (vocab = node_dim = hidden = 256)
#define NM 10000             // masked outputs
#define NMP 10048            // NM padded to 64-row blocks
#define NPB 256              // nodes per bucket
#define NBK 391              // buckets = ceil(NN/NPB)
#define BCAP 2560            // bucket capacity (mean 2048, +11 sigma)
#define TILE 4096            // edges per k_bin block
#define EBK ((NE + TILE - 1) / TILE) // 196 edge blocks

typedef __attribute__((ext_vector_type(8))) short bf16x8;
typedef __attribute__((ext_vector_type(4))) float f32x4;

__device__ __forceinline__ float bf2f(unsigned short u) {
    return __uint_as_float(((unsigned)u) << 16);
}
__device__ __forceinline__ unsigned short f2bf(float f) {
    unsigned u = __float_as_uint(f);
    u += 0x7fffu + ((u >> 16) & 1u);   // RNE
    return (unsigned short)(u >> 16);
}

// Round-7 structure minus the k_bhist ebuf pass:
//   k_bin counts carr[dst] via fire-and-forget atomics (measured ~free in
//   round 6: k_bin 43.5us with them = round-5 k_bin without).
//   k_nodes (replaces k_bhist) touches only per-node arrays: no 4MB ebuf
//   re-read, no 800k LDS hist atomics.
// Poison-typed maps (d_ws poisoned 0xAA):
//   mb[i]==1 masked; fb[i]==1 h1 needed; minfo[i]>0 masked, (>>1)-1 = row.
// Layer-2 co-allocation: node p owns [off[p],off[p]+c) L1, [off+c,off+2c) L2.
// nrec[cc] = (vocab, dinv, off, deg) -- k_expand worklist (compact h1c index).
// Overflow note: carr = true degree, placement capped at BCAP; divergence
// needs a +11-sigma bucket (P~1e-28) -- same class as existing drop guard.

__global__ void k_maskmap(const int* __restrict__ mpos, int* __restrict__ minfo,
                          unsigned char* __restrict__ mb, unsigned char* __restrict__ fb,
                          int* __restrict__ carr, int* __restrict__ gcur,
                          int* __restrict__ nctr) {
    int j = blockIdx.x * 256 + threadIdx.x;
    if (j < NN) carr[j] = 0;
    if (j < NM) {
        int p = mpos[j];
        minfo[p] = (j + 1) << 1;   // duplicates: any winner
        mb[p] = 1;
        fb[p] = 1;                 // masked pos needs h1 (self-loop)
    }
    if (j < NBK) gcur[j << 4] = j * BCAP;   // padded: 1 line per counter
    if (j == 0) *nctr = 0;
}

// LDS-staged multisplit binning + degree count (blocks < EBK, 1024 thr) +
// M1 build (next 64 blocks, 4 rows each) + W2t build (next 64 blocks)
__global__ __launch_bounds__(1024) void k_bin(
    const int* __restrict__ src, const int* __restrict__ dst,
    const unsigned char* __restrict__ mb, unsigned char* __restrict__ fb,
    int* __restrict__ carr,
    int* __restrict__ gcur, int* __restrict__ ebuf,
    const float* __restrict__ emb, const float* __restrict__ W1,
    const float* __restrict__ W2,
    unsigned short* __restrict__ M1, unsigned short* __restrict__ W2t) {
    __shared__ int lcnt[NBK];
    __shared__ int sd[TILE], ss[TILE];
    __shared__ float er4[4 * ND];
    int b = blockIdx.x, t = threadIdx.x;
    if (b >= EBK) {
        int bb = b - EBK;          // 0..127
        int row = t >> 8, col = t & 255;
        if (bb < 64) {             // M1 rows 4*bb .. 4*bb+3
            er4[t] = emb[(bb * 4) * ND + t];
            __syncthreads();
            float acc = 0.f;
            for (int k = 0; k < ND; k++) acc += er4[row * ND + k] * W1[k * ND + col];
            M1[(bb * 4 + row) * ND + col] = f2bf(acc);
        } else {                   // W2t rows 4*(bb-64) .. +3
            int n = (bb - 64) * 4 + row;
            W2t[n * ND + col] = f2bf(W2[col * ND + n]);
        }
        return;
    }
    for (int i = t; i < NBK; i += 1024) lcnt[i] = 0;
    __syncthreads();
    int e0 = b * TILE;
#pragma unroll
    for (int k = 0; k < TILE / 1024; k++) {
        int idx = t + k * 1024;
        int e = e0 + idx;
        if (e < NE) {
            int d = dst[e], s = src[e];
            sd[idx] = d; ss[idx] = s;
            atomicAdd(&lcnt[d >> 8], 1);
            atomicAdd(&carr[d], 1);      // fire-and-forget degree count
            if (mb[d] == 1) fb[s] = 1;   // benign-race byte store
        }
    }
    __syncthreads();
    for (int i = t; i < NBK; i += 1024) {
        int c = lcnt[i];
        lcnt[i] = c ? atomicAdd(&gcur[i << 4], c) : 0;
    }
    __syncthreads();
    int nv = min(NE - e0, TILE);
#pragma unroll
    for (int k = 0; k < TILE / 1024; k++) {
        int idx = t + k * 1024;
        if (idx < nv) {
            int d = sd[idx], s = ss[idx];
            int bk = d >> 8, j = d & 255;
            int pos = atomicAdd(&lcnt[bk], 1);
            if (pos < (bk + 1) * BCAP) ebuf[pos] = s | (j << 17);
        }
    }
}

// per-node finalize from carr (NO ebuf pass): dinv/xd4, compaction counter,
// per-bucket allocation-weight sum -> part[b] (raw, unscanned)
__global__ __launch_bounds__(256) void k_nodes(
    const int* __restrict__ x, const unsigned char* __restrict__ mb,
    const unsigned char* __restrict__ fb, const int* __restrict__ carr,
    int4* __restrict__ xd4, int* __restrict__ nctr, int* __restrict__ part) {
    __shared__ int rs[4];
    int b = blockIdx.x, t = threadIdx.x;
    int lane = t & 63, wv = t >> 6;
    int node = b * NPB + t;
    int w = 0;
    if (node < NN) {
        int c = carr[node];
        float dv = rsqrtf((float)c + 1.0f);
        int cc = 0;
        if (fb[node] == 1) cc = atomicAdd(nctr, 1);
        xd4[node] = make_int4(x[node], __float_as_int(dv), cc, 0);
        w = c + ((mb[node] == 1) ? c : 0);   // layer-1 + co-allocated layer-2
    }
#pragma unroll
    for (int o = 32; o >= 1; o >>= 1) w += __shfl_xor(w, o, 64);
    if (lane == 0) rs[wv] = w;
    __syncthreads();
    if (t == 0) part[b] = rs[0] + rs[1] + rs[2] + rs[3];
}

// CSR placement: block base = sum(part[0..b)) (L2-hot), node offsets via LDS
// 256-scan, publish off[node] + nrec[cc], place pairs via LDS-ranked cursors
__global__ __launch_bounds__(256) void k_place(
    const int* __restrict__ gcur, const int* __restrict__ ebuf,
    const int* __restrict__ minfo, const unsigned char* __restrict__ fb,
    const int* __restrict__ carr, const int* __restrict__ part,
    const int4* __restrict__ xd4, int* __restrict__ off, int2* __restrict__ pairs,
    int4* __restrict__ nrec) {
    __shared__ int sinfo[NPB], lc1[NPB], lc2[NPB];
    __shared__ int bred[4], wtot[4];
    int b = blockIdx.x, t = threadIdx.x;
    int lane = t & 63, wv = t >> 6;
    // block base: exclusive sum of raw per-bucket weights
    int pv = 0;
    for (int i = t; i < b; i += 256) pv += part[i];
#pragma unroll
    for (int o = 32; o >= 1; o >>= 1) pv += __shfl_xor(pv, o, 64);
    if (lane == 0) bred[wv] = pv;
    __syncthreads();
    int pbase = bred[0] + bred[1] + bred[2] + bred[3];
    // per-node offsets within bucket (all 256 threads are nodes)
    int node = b * NPB + t;
    int c = 0, m = 0, f = 0;
    if (node < NN) {
        c = carr[node];
        int mv = minfo[node];
        if (mv > 0) m = mv;
        f = (fb[node] == 1) ? 1 : 0;
    }
    int wgt = c + (m ? c : 0);
    int xx = wgt;
    for (int o = 1; o < 64; o <<= 1) { int y = __shfl_up(xx, o, 64); if (lane >= o) xx += y; }
    if (lane == 63) wtot[wv] = xx;
    __syncthreads();
    int wadd = 0;
#pragma unroll
    for (int k = 0; k < 4; k++) if (k < wv) wadd += wtot[k];
    int excl = xx - wgt + wadd;
    int myoff = pbase + excl;
    if (node < NN) {
        off[node] = myoff;
        if (f) {
            int4 xv = xd4[node];
            nrec[xv.z] = make_int4(xv.x, xv.y, myoff, c);   // vocab,dinv,off,deg
        }
    }
    sinfo[t] = m | f;
    lc1[t] = myoff;
    lc2[t] = myoff + c;
    __syncthreads();
    int n = min(gcur[b << 4] - b * BCAP, BCAP);
    int base = b * BCAP;
    for (int i = t; i < n; i += 256) {
        int w = ebuf[base + i];
        int j = w >> 17, s = w & 0x1FFFF;
        int ii = sinfo[j];
        if (ii == 0) continue;
        int4 xv = xd4[s];
        if (ii & 1) {
            int p = atomicAdd(&lc1[j], 1);       // LDS atomic
            pairs[p] = make_int2(xv.x, xv.y);    // (vocab, dinv) of src
        }
        if (ii > 1) {
            int p = atomicAdd(&lc2[j], 1);       // LDS atomic
            pairs[p] = make_int2(xv.z, xv.y);    // (compact idx, dinv)
        }
    }
}

// h1c[cc] = bf16(relu(dv_i*(sum_e w_e*M1[v_e] + dv_i*M1[x_i]) + b1))
// M1 (128 KiB) staged whole into LDS; persistent 256 blocks x 16 waves,
// grid-stride over fb nodes. Per-edge gather = conflict-free ds_read_b64.
__global__ __launch_bounds__(1024) void k_expand(
    const int* __restrict__ nctr, const int4* __restrict__ nrec,
    const int2* __restrict__ pairs,
    const unsigned short* __restrict__ M1,
    const float* __restrict__ b1,
    unsigned short* __restrict__ h1c) {
    __shared__ unsigned short sm1[ND * ND];      // 128 KiB (gfx950: 160 KiB/CU)
    int t = threadIdx.x;
    {
        const uint4* g = (const uint4*)M1;       // 16B vector staging
        uint4* s = (uint4*)sm1;
        for (int i = t; i < (ND * ND) / 8; i += 1024) s[i] = g[i];
    }
    __syncthreads();
    int lane = t & 63;
    float4 b1v = ((const float4*)b1)[lane];
    int nw = nctr[0];
    for (int idx = (blockIdx.x * 1024 + t) >> 6; idx < nw; idx += 4096) {
        int4 rec = nrec[idx];
        int v0 = rec.x;
        float w0 = __int_as_float(rec.y);
        ushort4 mm = *(const ushort4*)(sm1 + v0 * ND + lane * 4);
        float a0 = w0 * bf2f(mm.x), a1 = w0 * bf2f(mm.y);
        float a2 = w0 * bf2f(mm.z), a3 = w0 * bf2f(mm.w);
        int e = rec.z, end = e + rec.w;
        for (; e + 4 <= end; e += 4) {
            int2 pA = pairs[e + 0];
            int2 pB = pairs[e + 1];
            int2 pC = pairs[e + 2];
            int2 pD = pairs[e + 3];
            ushort4 mA = *(const ushort4*)(sm1 + pA.x * ND + lane * 4);
            ushort4 mB = *(const ushort4*)(sm1 + pB.x * ND + lane * 4);
            ushort4 mC = *(const ushort4*)(sm1 + pC.x * ND + lane * 4);
            ushort4 mD = *(const ushort4*)(sm1 + pD.x * ND + lane * 4);
            float wA = __int_as_float(pA.y), wB = __int_as_float(pB.y);
            float wC = __int_as_float(pC.y), wD = __int_as_float(pD.y);
            a0 += wA * bf2f(mA.x) + wB * bf2f(mB.x) + wC * bf2f(mC.x) + wD * bf2f(mD.x);
            a1 += wA * bf2f(mA.y) + wB * bf2f(mB.y) + wC * bf2f(mC.y) + wD * bf2f(mD.y);
            a2 += wA * bf2f(mA.z) + wB * bf2f(mB.z) + wC * bf2f(mC.z) + wD * bf2f(mD.z);
            a3 += wA * bf2f(mA.w) + wB * bf2f(mB.w) + wC * bf2f(mC.w) + wD * bf2f(mD.w);
        }
        for (; e < end; e++) {
            int2 p = pairs[e];
            float w = __int_as_float(p.y);
            ushort4 m2 = *(const ushort4*)(sm1 + p.x * ND + lane * 4);
            a0 += w * bf2f(m2.x);
            a1 += w * bf2f(m2.y);
            a2 += w * bf2f(m2.z);
            a3 += w * bf2f(m2.w);
        }
        ushort4 o;
        o.x = f2bf(fmaxf(fmaf(w0, a0, b1v.x), 0.f));
        o.y = f2bf(fmaxf(fmaf(w0, a1, b1v.y), 0.f));
        o.z = f2bf(fmaxf(fmaf(w0, a2, b1v.z), 0.f));
        o.w = f2bf(fmaxf(fmaf(w0, a3, b1v.w), 0.f));
        ((ushort4*)(h1c + (size_t)idx * ND))[lane] = o;
    }
}

// layer-2 aggregation + self-loop + dv scale, bf16 out (A-matrix rows for k_out2)
// layer-2 segment of masked node p: [off[p]+c, off[p]+2c)
__global__ void k_agg2(const int* __restrict__ mpos, const int* __restrict__ minfo,
                       const int4* __restrict__ xd4,
                       const int2* __restrict__ pairs, const int* __restrict__ off,
                       const int* __restrict__ carr,
                       const unsigned short* __restrict__ h1c,
                       unsigned short* __restrict__ agg2b) {
    int lane = threadIdx.x & 63;
    int wave = (blockIdx.x * 256 + threadIdx.x) >> 6;
    if (wave >= NM) return;
    int r = wave;
    int p = mpos[r];
    if ((minfo[p] >> 1) != r + 1) return;   // duplicate mask position: not representative
    int4 xp = xd4[p];
    int cp = xp.z;
    float dv = __int_as_float(xp.y);
    ushort4 h0 = *(const ushort4*)(h1c + (size_t)cp * ND + lane * 4);
    float a0 = dv * bf2f(h0.x), a1 = dv * bf2f(h0.y);
    float a2 = dv * bf2f(h0.z), a3 = dv * bf2f(h0.w);
    int c2 = carr[p];
    int e = off[p] + c2, end = e + c2;
    for (; e + 4 <= end; e += 4) {
        int2 pA = pairs[e + 0];
        int2 pB = pairs[e + 1];
        int2 pC = pairs[e + 2];
        int2 pD = pairs[e + 3];
        ushort4 hA = *(const ushort4*)(h1c + (size_t)pA.x * ND + lane * 4);
        ushort4 hB = *(const ushort4*)(h1c + (size_t)pB.x * ND + lane * 4);
        ushort4 hC = *(const ushort4*)(h1c + (size_t)pC.x * ND + lane * 4);
        ushort4 hD = *(const ushort4*)(h1c + (size_t)pD.x * ND + lane * 4);
        float wA = __int_as_float(pA.y), wB = __int_as_float(pB.y);
        float wC = __int_as_float(pC.y), wD = __int_as_float(pD.y);
        a0 += wA * bf2f(hA.x) + wB * bf2f(hB.x) + wC * bf2f(hC.x) + wD * bf2f(hD.x);
        a1 += wA * bf2f(hA.y) + wB * bf2f(hB.y) + wC * bf2f(hC.y) + wD * bf2f(hD.y);
        a2 += wA * bf2f(hA.z) + wB * bf2f(hB.z) + wC * bf2f(hC.z) + wD * bf2f(hD.z);
        a3 += wA * bf2f(hA.w) + wB * bf2f(hB.w) + wC * bf2f(hC.w) + wD * bf2f(hD.w);
    }
    for (; e < end; e++) {
        int2 pp = pairs[e];
        float w = __int_as_float(pp.y);
        ushort4 hv = *(const ushort4*)(h1c + (size_t)pp.x * ND + lane * 4);
        a0 += w * bf2f(hv.x);
        a1 += w * bf2f(hv.y);
        a2 += w * bf2f(hv.z);
        a3 += w * bf2f(hv.w);
    }
    ushort4 o;
    o.x = f2bf(dv * a0);
    o.y = f2bf(dv * a1);
    o.z = f2bf(dv * a2);
    o.w = f2bf(dv * a3);
    ((ushort4*)(agg2b + (size_t)r * ND))[lane] = o;
}

// MFMA GEMM + log-softmax: out[j] = log_softmax(agg2b[rep(j)] @ W2 + b2)
__global__ __launch_bounds__(256) void k_out2(
    const int* __restrict__ mpos, const int* __restrict__ minfo,
    const unsigned short* __restrict__ agg2b, const unsigned short* __restrict__ W2t,
    const float* __restrict__ b2, float* __restrict__ out) {
    int lane = threadIdx.x & 63;
    int wv = threadIdx.x >> 6;
    int row0 = blockIdx.x * 64 + wv * 16;   // 16 rows per wave
    int qm = lane & 15, qk = lane >> 4;
    int row = row0 + qm;
    bf16x8 afr[8];
    if (row < NM) {
        int p = mpos[row];
        int rr = (minfo[p] >> 1) - 1;
        const unsigned short* arow = agg2b + (size_t)rr * ND + qk * 8;
#pragma unroll
        for (int kt = 0; kt < 8; kt++) afr[kt] = *(const bf16x8*)(arow + kt * 32);
    } else {
#pragma unroll
        for (int kt = 0; kt < 8; kt++) afr[kt] = (bf16x8){0, 0, 0, 0, 0, 0, 0, 0};
    }
    f32x4 acc[16];
#pragma unroll
    for (int t = 0; t < 16; t++) acc[t] = (f32x4){0.f, 0.f, 0.f, 0.f};
#pragma unroll
    for (int t = 0; t < 16; t++) {
        const unsigned short* brow = W2t + (size_t)(t * 16 + qm) * ND + qk * 8;
#pragma unroll
        for (int kt = 0; kt < 8; kt++) {
            bf16x8 bfr = *(const bf16x8*)(brow + kt * 32);
            acc[t] = __builtin_amdgcn_mfma_f32_16x16x32_bf16(afr[kt], bfr, acc[t], 0, 0, 0);
        }
    }
    float mx[4] = {-1e30f, -1e30f, -1e30f, -1e30f};
#pragma unroll
    for (int t = 0; t < 16; t++) {
        float cb = b2[qm + 16 * t];
#pragma unroll
        for (int r = 0; r < 4; r++) {
            float v = acc[t][r] + cb;
            acc[t][r] = v;
            mx[r] = fmaxf(mx[r], v);
        }
    }
#pragma unroll
    for (int r = 0; r < 4; r++)
        for (int o = 1; o < 16; o <<= 1) mx[r] = fmaxf(mx[r], __shfl_xor(mx[r], o, 64));
    float sm[4] = {0.f, 0.f, 0.f, 0.f};
#pragma unroll
    for (int t = 0; t < 16; t++)
#pragma unroll
        for (int r = 0; r < 4; r++) sm[r] += __expf(acc[t][r] - mx[r]);
#pragma unroll
    for (int r = 0; r < 4; r++)
        for (int o = 1; o < 16; o <<= 1) sm[r] += __shfl_xor(sm[r], o, 64);
#pragma unroll
    for (int r = 0; r < 4; r++) {
        int orow_i = row0 + qk * 4 + r;
        if (orow_i >= NM) continue;
        float lse = mx[r] + __logf(sm[r]);
        float* orow = out + (size_t)orow_i * ND + qm;
#pragma unroll
        for (int t = 0; t < 16; t++) orow[16 * t] = acc[t][r] - lse;
    }
}

extern "C" void kernel_launch(void* const* d_in, const int* in_sizes, int n_in,
                              void* d_out, int out_size, void* d_ws, size_t ws_size,
                              hipStream_t stream) {
    const int* x    = (const int*)d_in[0];
    const int* ei   = (const int*)d_in[1];
    const int* src  = ei;
    const int* dst  = ei + NE;
    const int* mpos = (const int*)d_in[2];
    const float* emb = (const float*)d_in[3];
    const float* W1  = (const float*)d_in[4];
    const float* b1  = (const float*)d_in[5];
    const float* W2  = (const float*)d_in[6];
    const float* b2  = (const float*)d_in[7];
    float* out = (float*)d_out;

    char* w = (char*)d_ws;
    size_t o = 0;
#define ALLOC(nbytes) ({ void* _p = (void*)(w + o); o = (o + (size_t)(nbytes) + 63) & ~(size_t)63; _p; })
    int*   carr  = (int*)ALLOC((size_t)(NN + 64) * 4);
    int*   off   = (int*)ALLOC((size_t)(NN + 64) * 4);
    int*   minfo = (int*)ALLOC((size_t)NN * 4);
    unsigned char* mb = (unsigned char*)ALLOC(NN + 64);
    unsigned char* fb = (unsigned char*)ALLOC(NN + 64);
    int4*  xd4   = (int4*)ALLOC((size_t)NN * 16);                        // 1.6 MB
    int*   nctr  = (int*)ALLOC(64);
    int*   part  = (int*)ALLOC(512 * 4);                                 // NBK partials
    int*   gcur  = (int*)ALLOC((size_t)(NBK * 16 + 64) * 4);             // 1 line/counter
    int*   ebuf  = (int*)ALLOC((size_t)NBK * BCAP * 4);                  // 4.0 MB
    unsigned short* M1    = (unsigned short*)ALLOC((size_t)ND * ND * 2);
    unsigned short* W2t   = (unsigned short*)ALLOC((size_t)ND * ND * 2);
    unsigned short* agg2b = (unsigned short*)ALLOC((size_t)NM * ND * 2); // 5.1 MB
    int2*  pairs = (int2*)ALLOC((size_t)NE * 2 * 8);                     // 12.8 MB
    int4*  nrec  = (int4*)ALLOC((size_t)NN * 16);                        // 1.6 MB
    unsigned short* h1c  = (unsigned short*)ALLOC((size_t)NN * ND * 2);  // 51.2 MB
#undef ALLOC

    k_maskmap<<<(NN + 255) / 256, 256, 0, stream>>>(mpos, minfo, mb, fb, carr, gcur, nctr);
    k_bin<<<EBK + 128, 1024, 0, stream>>>(src, dst, mb, fb, carr, gcur, ebuf,
                                          emb, W1, W2, M1, W2t);
    k_nodes<<<NBK, 256, 0, stream>>>(x, mb, fb, carr, xd4, nctr, part);
    k_place<<<NBK, 256, 0, stream>>>(gcur, ebuf, minfo, fb, carr, part, xd4, off, pairs, nrec);
    k_expand<<<256, 1024, 0, stream>>>(nctr, nrec, pairs, M1, b1, h1c);
    k_agg2<<<(NM + 3) / 4, 256, 0, stream>>>(mpos, minfo, xd4, pairs, off, carr, h1c, agg2b);
    k_out2<<<NMP / 64, 256, 0, stream>>>(mpos, minfo, agg2b, W2t, b2, out);
}

// Round 10
// 212.429 us; speedup vs baseline: 1.0151x; 1.0151x over previous
//
#include <hip/hip_runtime.h>
#include <stdint.h>

#define NN 100000            // nodes
#define NE 800000            // edges
#define ND 256               // dim (vocab = node_dim = hidden = 256)
#define NM 10000             // masked outputs
#define NMP 10048            // NM padded to 64-row blocks
#define NPB 256              // nodes per bucket
#define NBK 391              // buckets = ceil(NN/NPB)
#define BCAP 2560            // bucket capacity (mean 2048, +11 sigma)
#define TILE 4096            // edges per k_bin block
#define EBK ((NE + TILE - 1) / TILE) // 196 edge blocks

typedef __attribute__((ext_vector_type(8))) short bf16x8;
typedef __attribute__((ext_vector_type(4))) float f32x4;

__device__ __forceinline__ float bf2f(unsigned short u) {
    return __uint_as_float(((unsigned)u) << 16);
}
__device__ __forceinline__ unsigned short f2bf(float f) {
    unsigned u = __float_as_uint(f);
    u += 0x7fffu + ((u >> 16) & 1u);   // RNE
    return (unsigned short)(u >> 16);
}

// Composition of measured-good pieces:
//   k_bin = round-6's exact 256-thr TILE=4096 version WITH carr counting
//     (measured 43.5us) -> k_bhist eliminated, k_nodes reads carr only.
//   pairs payload packed to 4B: L1 = vocab<<8|deg, L2 = cc<<8|deg;
//     consumers recompute dinv = rsqrtf(deg+1) (bit-identical to stored f32).
//   xd4 = (vocab, dinv, cc, min(deg,255)).
// Poison-typed maps (d_ws poisoned 0xAA):
//   mb[i]==1 masked; fb[i]==1 h1 needed; minfo[i]>0 masked, (>>1)-1 = row.
// Layer-2 co-allocation: node p owns [off[p],off[p]+c) L1, [off+c,off+2c) L2.
// nrec[cc] = (vocab, dinv, off, deg) -- k_expand worklist (compact h1c index).
// Overflow note: carr = true degree, placement capped at BCAP; divergence
// needs a +11-sigma bucket (P~1e-28) -- same class as existing drop guard.

__global__ void k_maskmap(const int* __restrict__ mpos, int* __restrict__ minfo,
                          unsigned char* __restrict__ mb, unsigned char* __restrict__ fb,
                          int* __restrict__ carr, int* __restrict__ gcur,
                          int* __restrict__ nctr) {
    int j = blockIdx.x * 256 + threadIdx.x;
    if (j < NN) carr[j] = 0;
    if (j < NM) {
        int p = mpos[j];
        minfo[p] = (j + 1) << 1;   // duplicates: any winner
        mb[p] = 1;
        fb[p] = 1;                 // masked pos needs h1 (self-loop)
    }
    if (j < NBK) gcur[j << 4] = j * BCAP;   // padded: 1 line per counter
    if (j == 0) *nctr = 0;
}

// LDS-staged multisplit binning + degree count (blocks < EBK, 256 thr --
// round-6's measured-43.5us config) + M1/W2t build (blocks >= EBK)
__global__ __launch_bounds__(256) void k_bin(
    const int* __restrict__ src, const int* __restrict__ dst,
    const unsigned char* __restrict__ mb, unsigned char* __restrict__ fb,
    int* __restrict__ carr,
    int* __restrict__ gcur, int* __restrict__ ebuf,
    const float* __restrict__ emb, const float* __restrict__ W1,
    const float* __restrict__ W2,
    unsigned short* __restrict__ M1, unsigned short* __restrict__ W2t) {
    __shared__ int lcnt[NBK];
    __shared__ int sd[TILE], ss[TILE];
    __shared__ float er[ND];
    int b = blockIdx.x, t = threadIdx.x;
    if (b >= EBK) {
        int bb = b - EBK;          // 0..511
        if (bb < ND) {
            er[t] = emb[bb * ND + t];
            __syncthreads();
            float acc = 0.f;
            for (int k = 0; k < ND; k++) acc += er[k] * W1[k * ND + t];
            M1[bb * ND + t] = f2bf(acc);
        } else {
            int n = bb - ND;
            W2t[n * ND + t] = f2bf(W2[t * ND + n]);
        }
        return;
    }
    for (int i = t; i < NBK; i += 256) lcnt[i] = 0;
    __syncthreads();
    int e0 = b * TILE;
#pragma unroll
    for (int k = 0; k < TILE / 256; k++) {
        int idx = t + k * 256;
        int e = e0 + idx;
        if (e < NE) {
            int d = dst[e], s = src[e];
            sd[idx] = d; ss[idx] = s;
            atomicAdd(&lcnt[d >> 8], 1);
            atomicAdd(&carr[d], 1);      // fire-and-forget degree count
            if (mb[d] == 1) fb[s] = 1;   // benign-race byte store
        }
    }
    __syncthreads();
    for (int i = t; i < NBK; i += 256) {
        int c = lcnt[i];
        lcnt[i] = c ? atomicAdd(&gcur[i << 4], c) : 0;
    }
    __syncthreads();
    int nv = min(NE - e0, TILE);
#pragma unroll
    for (int k = 0; k < TILE / 256; k++) {
        int idx = t + k * 256;
        if (idx < nv) {
            int d = sd[idx], s = ss[idx];
            int bk = d >> 8, j = d & 255;
            int pos = atomicAdd(&lcnt[bk], 1);
            if (pos < (bk + 1) * BCAP) ebuf[pos] = s | (j << 17);
        }
    }
}

// per-node finalize from carr (NO ebuf pass): dinv/xd4, compaction counter,
// per-bucket allocation-weight sum -> part[b] (raw, unscanned)
__global__ __launch_bounds__(256) void k_nodes(
    const int* __restrict__ x, const unsigned char* __restrict__ mb,
    const unsigned char* __restrict__ fb, const int* __restrict__ carr,
    int4* __restrict__ xd4, int* __restrict__ nctr, int* __restrict__ part) {
    __shared__ int rs[4];
    int b = blockIdx.x, t = threadIdx.x;
    int lane = t & 63, wv = t >> 6;
    int node = b * NPB + t;
    int w = 0;
    if (node < NN) {
        int c = carr[node];
        float dv = rsqrtf((float)c + 1.0f);
        int cc = 0;
        if (fb[node] == 1) cc = atomicAdd(nctr, 1);
        xd4[node] = make_int4(x[node], __float_as_int(dv), cc, min(c, 255));
        w = c + ((mb[node] == 1) ? c : 0);   // layer-1 + co-allocated layer-2
    }
#pragma unroll
    for (int o = 32; o >= 1; o >>= 1) w += __shfl_xor(w, o, 64);
    if (lane == 0) rs[wv] = w;
    __syncthreads();
    if (t == 0) part[b] = rs[0] + rs[1] + rs[2] + rs[3];
}

// CSR placement: block base = sum(part[0..b)) (L2-hot), node offsets via LDS
// 256-scan, publish off[node] + nrec[cc], place PACKED 4B pairs via
// LDS-ranked cursors
__global__ __launch_bounds__(256) void k_place(
    const int* __restrict__ gcur, const int* __restrict__ ebuf,
    const int* __restrict__ minfo, const unsigned char* __restrict__ fb,
    const int* __restrict__ carr, const int* __restrict__ part,
    const int4* __restrict__ xd4, int* __restrict__ off, int* __restrict__ pairs,
    int4* __restrict__ nrec) {
    __shared__ int sinfo[NPB], lc1[NPB], lc2[NPB];
    __shared__ int bred[4], wtot[4];
    int b = blockIdx.x, t = threadIdx.x;
    int lane = t & 63, wv = t >> 6;
    // block base: exclusive sum of raw per-bucket weights
    int pv = 0;
    for (int i = t; i < b; i += 256) pv += part[i];
#pragma unroll
    for (int o = 32; o >= 1; o >>= 1) pv += __shfl_xor(pv, o, 64);
    if (lane == 0) bred[wv] = pv;
    __syncthreads();
    int pbase = bred[0] + bred[1] + bred[2] + bred[3];
    // per-node offsets within bucket (all 256 threads are nodes)
    int node = b * NPB + t;
    int c = 0, m = 0, f = 0;
    if (node < NN) {
        c = carr[node];
        int mv = minfo[node];
        if (mv > 0) m = mv;
        f = (fb[node] == 1) ? 1 : 0;
    }
    int wgt = c + (m ? c : 0);
    int xx = wgt;
    for (int o = 1; o < 64; o <<= 1) { int y = __shfl_up(xx, o, 64); if (lane >= o) xx += y; }
    if (lane == 63) wtot[wv] = xx;
    __syncthreads();
    int wadd = 0;
#pragma unroll
    for (int k = 0; k < 4; k++) if (k < wv) wadd += wtot[k];
    int excl = xx - wgt + wadd;
    int myoff = pbase + excl;
    if (node < NN) {
        off[node] = myoff;
        if (f) {
            int4 xv = xd4[node];
            nrec[xv.z] = make_int4(xv.x, xv.y, myoff, c);   // vocab,dinv,off,deg
        }
    }
    sinfo[t] = m | f;
    lc1[t] = myoff;
    lc2[t] = myoff + c;
    __syncthreads();
    int n = min(gcur[b << 4] - b * BCAP, BCAP);
    int base = b * BCAP;
    for (int i = t; i < n; i += 256) {
        int w = ebuf[base + i];
        int j = w >> 17, s = w & 0x1FFFF;
        int ii = sinfo[j];
        if (ii == 0) continue;
        int4 xv = xd4[s];
        if (ii & 1) {
            int p = atomicAdd(&lc1[j], 1);       // LDS atomic
            pairs[p] = (xv.x << 8) | xv.w;       // vocab<<8 | deg
        }
        if (ii > 1) {
            int p = atomicAdd(&lc2[j], 1);       // LDS atomic
            pairs[p] = (xv.z << 8) | xv.w;       // cc<<8 | deg
        }
    }
}

// h1c[cc] = bf16(relu(dv_i*(sum_e w_e*M1[v_e] + dv_i*M1[x_i]) + b1))
// M1 (128 KiB) staged whole into LDS; persistent 256 blocks x 16 waves,
// grid-stride over fb nodes. dinv_s = rsqrtf(deg+1) recomputed (bit-identical).
__global__ __launch_bounds__(1024) void k_expand(
    const int* __restrict__ nctr, const int4* __restrict__ nrec,
    const int* __restrict__ pairs,
    const unsigned short* __restrict__ M1,
    const float* __restrict__ b1,
    unsigned short* __restrict__ h1c) {
    __shared__ unsigned short sm1[ND * ND];      // 128 KiB (gfx950: 160 KiB/CU)
    int t = threadIdx.x;
    {
        const uint4* g = (const uint4*)M1;       // 16B vector staging
        uint4* s = (uint4*)sm1;
        for (int i = t; i < (ND * ND) / 8; i += 1024) s[i] = g[i];
    }
    __syncthreads();
    int lane = t & 63;
    float4 b1v = ((const float4*)b1)[lane];
    int nw = nctr[0];
    for (int idx = (blockIdx.x * 1024 + t) >> 6; idx < nw; idx += 4096) {
        int4 rec = nrec[idx];
        int v0 = rec.x;
        float w0 = __int_as_float(rec.y);
        ushort4 mm = *(const ushort4*)(sm1 + v0 * ND + lane * 4);
        float a0 = w0 * bf2f(mm.x), a1 = w0 * bf2f(mm.y);
        float a2 = w0 * bf2f(mm.z), a3 = w0 * bf2f(mm.w);
        int e = rec.z, end = e + rec.w;
        for (; e + 4 <= end; e += 4) {
            int pA = pairs[e + 0];
            int pB = pairs[e + 1];
            int pC = pairs[e + 2];
            int pD = pairs[e + 3];
            ushort4 mA = *(const ushort4*)(sm1 + (pA >> 8) * ND + lane * 4);
            ushort4 mB = *(const ushort4*)(sm1 + (pB >> 8) * ND + lane * 4);
            ushort4 mC = *(const ushort4*)(sm1 + (pC >> 8) * ND + lane * 4);
            ushort4 mD = *(const ushort4*)(sm1 + (pD >> 8) * ND + lane * 4);
            float wA = rsqrtf((float)(pA & 255) + 1.0f);
            float wB = rsqrtf((float)(pB & 255) + 1.0f);
            float wC = rsqrtf((float)(pC & 255) + 1.0f);
            float wD = rsqrtf((float)(pD & 255) + 1.0f);
            a0 += wA * bf2f(mA.x) + wB * bf2f(mB.x) + wC * bf2f(mC.x) + wD * bf2f(mD.x);
            a1 += wA * bf2f(mA.y) + wB * bf2f(mB.y) + wC * bf2f(mC.y) + wD * bf2f(mD.y);
            a2 += wA * bf2f(mA.z) + wB * bf2f(mB.z) + wC * bf2f(mC.z) + wD * bf2f(mD.z);
            a3 += wA * bf2f(mA.w) + wB * bf2f(mB.w) + wC * bf2f(mC.w) + wD * bf2f(mD.w);
        }
        for (; e < end; e++) {
            int p = pairs[e];
            float w = rsqrtf((float)(p & 255) + 1.0f);
            ushort4 m2 = *(const ushort4*)(sm1 + (p >> 8) * ND + lane * 4);
            a0 += w * bf2f(m2.x);
            a1 += w * bf2f(m2.y);
            a2 += w * bf2f(m2.z);
            a3 += w * bf2f(m2.w);
        }
        ushort4 o;
        o.x = f2bf(fmaxf(fmaf(w0, a0, b1v.x), 0.f));
        o.y = f2bf(fmaxf(fmaf(w0, a1, b1v.y), 0.f));
        o.z = f2bf(fmaxf(fmaf(w0, a2, b1v.z), 0.f));
        o.w = f2bf(fmaxf(fmaf(w0, a3, b1v.w), 0.f));
        ((ushort4*)(h1c + (size_t)idx * ND))[lane] = o;
    }
}

// layer-2 aggregation + self-loop + dv scale, bf16 out (A-matrix rows for k_out2)
// layer-2 segment of masked node p: [off[p]+c, off[p]+2c)
__global__ void k_agg2(const int* __restrict__ mpos, const int* __restrict__ minfo,
                       const int4* __restrict__ xd4,
                       const int* __restrict__ pairs, const int* __restrict__ off,
                       const int* __restrict__ carr,
                       const unsigned short* __restrict__ h1c,
                       unsigned short* __restrict__ agg2b) {
    int lane = threadIdx.x & 63;
    int wave = (blockIdx.x * 256 + threadIdx.x) >> 6;
    if (wave >= NM) return;
    int r = wave;
    int p = mpos[r];
    if ((minfo[p] >> 1) != r + 1) return;   // duplicate mask position: not representative
    int4 xp = xd4[p];
    int cp = xp.z;
    float dv = __int_as_float(xp.y);
    ushort4 h0 = *(const ushort4*)(h1c + (size_t)cp * ND + lane * 4);
    float a0 = dv * bf2f(h0.x), a1 = dv * bf2f(h0.y);
    float a2 = dv * bf2f(h0.z), a3 = dv * bf2f(h0.w);
    int c2 = carr[p];
    int e = off[p] + c2, end = e + c2;
    for (; e + 4 <= end; e += 4) {
        int pA = pairs[e + 0];
        int pB = pairs[e + 1];
        int pC = pairs[e + 2];
        int pD = pairs[e + 3];
        ushort4 hA = *(const ushort4*)(h1c + (size_t)(pA >> 8) * ND + lane * 4);
        ushort4 hB = *(const ushort4*)(h1c + (size_t)(pB >> 8) * ND + lane * 4);
        ushort4 hC = *(const ushort4*)(h1c + (size_t)(pC >> 8) * ND + lane * 4);
        ushort4 hD = *(const ushort4*)(h1c + (size_t)(pD >> 8) * ND + lane * 4);
        float wA = rsqrtf((float)(pA & 255) + 1.0f);
        float wB = rsqrtf((float)(pB & 255) + 1.0f);
        float wC = rsqrtf((float)(pC & 255) + 1.0f);
        float wD = rsqrtf((float)(pD & 255) + 1.0f);
        a0 += wA * bf2f(hA.x) + wB * bf2f(hB.x) + wC * bf2f(hC.x) + wD * bf2f(hD.x);
        a1 += wA * bf2f(hA.y) + wB * bf2f(hB.y) + wC * bf2f(hC.y) + wD * bf2f(hD.y);
        a2 += wA * bf2f(hA.z) + wB * bf2f(hB.z) + wC * bf2f(hC.z) + wD * bf2f(hD.z);
        a3 += wA * bf2f(hA.w) + wB * bf2f(hB.w) + wC * bf2f(hC.w) + wD * bf2f(hD.w);
    }
    for (; e < end; e++) {
        int pp = pairs[e];
        float w = rsqrtf((float)(pp & 255) + 1.0f);
        ushort4 hv = *(const ushort4*)(h1c + (size_t)(pp >> 8) * ND + lane * 4);
        a0 += w * bf2f(hv.x);
        a1 += w * bf2f(hv.y);
        a2 += w * bf2f(hv.z);
        a3 += w * bf2f(hv.w);
    }
    ushort4 o;
    o.x = f2bf(dv * a0);
    o.y = f2bf(dv * a1);
    o.z = f2bf(dv * a2);
    o.w = f2bf(dv * a3);
    ((ushort4*)(agg2b + (size_t)r * ND))[lane] = o;
}

// MFMA GEMM + log-softmax: out[j] = log_softmax(agg2b[rep(j)] @ W2 + b2)
__global__ __launch_bounds__(256) void k_out2(
    const int* __restrict__ mpos, const int* __restrict__ minfo,
    const unsigned short* __restrict__ agg2b, const unsigned short* __restrict__ W2t,
    const float* __restrict__ b2, float* __restrict__ out) {
    int lane = threadIdx.x & 63;
    int wv = threadIdx.x >> 6;
    int row0 = blockIdx.x * 64 + wv * 16;   // 16 rows per wave
    int qm = lane & 15, qk = lane >> 4;
    int row = row0 + qm;
    bf16x8 afr[8];
    if (row < NM) {
        int p = mpos[row];
        int rr = (minfo[p] >> 1) - 1;
        const unsigned short* arow = agg2b + (size_t)rr * ND + qk * 8;
#pragma unroll
        for (int kt = 0; kt < 8; kt++) afr[kt] = *(const bf16x8*)(arow + kt * 32);
    } else {
#pragma unroll
        for (int kt = 0; kt < 8; kt++) afr[kt] = (bf16x8){0, 0, 0, 0, 0, 0, 0, 0};
    }
    f32x4 acc[16];
#pragma unroll
    for (int t = 0; t < 16; t++) acc[t] = (f32x4){0.f, 0.f, 0.f, 0.f};
#pragma unroll
    for (int t = 0; t < 16; t++) {
        const unsigned short* brow = W2t + (size_t)(t * 16 + qm) * ND + qk * 8;
#pragma unroll
        for (int kt = 0; kt < 8; kt++) {
            bf16x8 bfr = *(const bf16x8*)(brow + kt * 32);
            acc[t] = __builtin_amdgcn_mfma_f32_16x16x32_bf16(afr[kt], bfr, acc[t], 0, 0, 0);
        }
    }
    float mx[4] = {-1e30f, -1e30f, -1e30f, -1e30f};
#pragma unroll
    for (int t = 0; t < 16; t++) {
        float cb = b2[qm + 16 * t];
#pragma unroll
        for (int r = 0; r < 4; r++) {
            float v = acc[t][r] + cb;
            acc[t][r] = v;
            mx[r] = fmaxf(mx[r], v);
        }
    }
#pragma unroll
    for (int r = 0; r < 4; r++)
        for (int o = 1; o < 16; o <<= 1) mx[r] = fmaxf(mx[r], __shfl_xor(mx[r], o, 64));
    float sm[4] = {0.f, 0.f, 0.f, 0.f};
#pragma unroll
    for (int t = 0; t < 16; t++)
#pragma unroll
        for (int r = 0; r < 4; r++) sm[r] += __expf(acc[t][r] - mx[r]);
#pragma unroll
    for (int r = 0; r < 4; r++)
        for (int o = 1; o < 16; o <<= 1) sm[r] += __shfl_xor(sm[r], o, 64);
#pragma unroll
    for (int r = 0; r < 4; r++) {
        int orow_i = row0 + qk * 4 + r;
        if (orow_i >= NM) continue;
        float lse = mx[r] + __logf(sm[r]);
        float* orow = out + (size_t)orow_i * ND + qm;
#pragma unroll
        for (int t = 0; t < 16; t++) orow[16 * t] = acc[t][r] - lse;
    }
}

extern "C" void kernel_launch(void* const* d_in, const int* in_sizes, int n_in,
                              void* d_out, int out_size, void* d_ws, size_t ws_size,
                              hipStream_t stream) {
    const int* x    = (const int*)d_in[0];
    const int* ei   = (const int*)d_in[1];
    const int* src  = ei;
    const int* dst  = ei + NE;
    const int* mpos = (const int*)d_in[2];
    const float* emb = (const float*)d_in[3];
    const float* W1  = (const float*)d_in[4];
    const float* b1  = (const float*)d_in[5];
    const float* W2  = (const float*)d_in[6];
    const float* b2  = (const float*)d_in[7];
    float* out = (float*)d_out;

    char* w = (char*)d_ws;
    size_t o = 0;
#define ALLOC(nbytes) ({ void* _p = (void*)(w + o); o = (o + (size_t)(nbytes) + 63) & ~(size_t)63; _p; })
    int*   carr  = (int*)ALLOC((size_t)(NN + 64) * 4);
    int*   off   = (int*)ALLOC((size_t)(NN + 64) * 4);
    int*   minfo = (int*)ALLOC((size_t)NN * 4);
    unsigned char* mb = (unsigned char*)ALLOC(NN + 64);
    unsigned char* fb = (unsigned char*)ALLOC(NN + 64);
    int4*  xd4   = (int4*)ALLOC((size_t)NN * 16);                        // 1.6 MB
    int*   nctr  = (int*)ALLOC(64);
    int*   part  = (int*)ALLOC(512 * 4);                                 // NBK partials
    int*   gcur  = (int*)ALLOC((size_t)(NBK * 16 + 64) * 4);             // 1 line/counter
    int*   ebuf  = (int*)ALLOC((size_t)NBK * BCAP * 4);                  // 4.0 MB
    unsigned short* M1    = (unsigned short*)ALLOC((size_t)ND * ND * 2);
    unsigned short* W2t   = (unsigned short*)ALLOC((size_t)ND * ND * 2);
    unsigned short* agg2b = (unsigned short*)ALLOC((size_t)NM * ND * 2); // 5.1 MB
    int*   pairs = (int*)ALLOC((size_t)NE * 2 * 4);                      // 6.4 MB packed
    int4*  nrec  = (int4*)ALLOC((size_t)NN * 16);                        // 1.6 MB
    unsigned short* h1c  = (unsigned short*)ALLOC((size_t)NN * ND * 2);  // 51.2 MB
#undef ALLOC

    k_maskmap<<<(NN + 255) / 256, 256, 0, stream>>>(mpos, minfo, mb, fb, carr, gcur, nctr);
    k_bin<<<EBK + 2 * ND, 256, 0, stream>>>(src, dst, mb, fb, carr, gcur, ebuf,
                                            emb, W1, W2, M1, W2t);
    k_nodes<<<NBK, 256, 0, stream>>>(x, mb, fb, carr, xd4, nctr, part);
    k_place<<<NBK, 256, 0, stream>>>(gcur, ebuf, minfo, fb, carr, part, xd4, off, pairs, nrec);
    k_expand<<<256, 1024, 0, stream>>>(nctr, nrec, pairs, M1, b1, h1c);
    k_agg2<<<(NM + 3) / 4, 256, 0, stream>>>(mpos, minfo, xd4, pairs, off, carr, h1c, agg2b);
    k_out2<<<NMP / 64, 256, 0, stream>>>(mpos, minfo, agg2b, W2t, b2, out);
}

// Round 11
// 190.442 us; speedup vs baseline: 1.1323x; 1.1155x over previous
//
#include <hip/hip_runtime.h>
#include <stdint.h>

#define NN 100000            // nodes
#define NE 800000            // edges
#define ND 256               // dim (vocab = node_dim = hidden = 256)
#define NM 10000             // masked outputs
#define NMP 10048            // NM padded to 64-row blocks
#define NPB 256              // nodes per bucket
#define NBK 391              // buckets = ceil(NN/NPB)
#define BCAP 2560            // bucket capacity (mean 2048, +11 sigma)
#define TILE 4096            // edges per k_bin block
#define EBK ((NE + TILE - 1) / TILE) // 196 edge blocks

typedef __attribute__((ext_vector_type(8))) short bf16x8;
typedef __attribute__((ext_vector_type(4))) float f32x4;

__device__ __forceinline__ float bf2f(unsigned short u) {
    return __uint_as_float(((unsigned)u) << 16);
}
__device__ __forceinline__ unsigned short f2bf(float f) {
    unsigned u = __float_as_uint(f);
    u += 0x7fffu + ((u >> 16) & 1u);   // RNE
    return (unsigned short)(u >> 16);
}

// Round-7 verbatim re-submit (best measured: 189.7us).
// Session findings baked in:
//   - carr atomics in k_bin cost ~20us SYSTEM-wide (r6/r9/r10 all 208-215)
//     despite k_bin's own time being flat -- cross-XCD dirty-line effect.
//     Histogram front-end (k_bhist) is the measured-best degree source.
//   - k_bin is pinned at ~43-49us in every config (256/1024 thr, +-carr,
//     TILE 1024/4096): structurally latency/scatter-bound, not tunable.
//   - Front-end totals: this structure = 190 floor; all variants regress.
// Poison-typed maps (d_ws poisoned 0xAA; no zero-init anywhere):
//   mb[i]==1 masked; fb[i]==1 h1 needed; minfo[i]>0 masked, (>>1)-1 = row.
// Layer-2 co-allocation: node p owns [off[p],off[p]+c) L1, [off+c,off+2c) L2.
// nrec[cc] = (vocab, dinv, off, deg) -- k_expand worklist (compact h1c index).

__global__ void k_maskmap(const int* __restrict__ mpos, int* __restrict__ minfo,
                          unsigned char* __restrict__ mb, unsigned char* __restrict__ fb,
                          int* __restrict__ gcur, int* __restrict__ nctr) {
    int j = blockIdx.x * 256 + threadIdx.x;
    if (j < NM) {
        int p = mpos[j];
        minfo[p] = (j + 1) << 1;   // duplicates: any winner
        mb[p] = 1;
        fb[p] = 1;                 // masked pos needs h1 (self-loop)
    }
    if (j < NBK) gcur[j << 4] = j * BCAP;   // padded: 1 line per counter
    if (j == 0) *nctr = 0;
}

// LDS-staged multisplit binning (blocks < EBK, 1024 thr) +
// M1 build (next 64 blocks, 4 rows each) + W2t build (next 64 blocks)
__global__ __launch_bounds__(1024) void k_bin(
    const int* __restrict__ src, const int* __restrict__ dst,
    const unsigned char* __restrict__ mb, unsigned char* __restrict__ fb,
    int* __restrict__ gcur, int* __restrict__ ebuf,
    const float* __restrict__ emb, const float* __restrict__ W1,
    const float* __restrict__ W2,
    unsigned short* __restrict__ M1, unsigned short* __restrict__ W2t) {
    __shared__ int lcnt[NBK];
    __shared__ int sd[TILE], ss[TILE];
    __shared__ float er4[4 * ND];
    int b = blockIdx.x, t = threadIdx.x;
    if (b >= EBK) {
        int bb = b - EBK;          // 0..127
        int row = t >> 8, col = t & 255;
        if (bb < 64) {             // M1 rows 4*bb .. 4*bb+3
            er4[t] = emb[(bb * 4) * ND + t];
            __syncthreads();
            float acc = 0.f;
            for (int k = 0; k < ND; k++) acc += er4[row * ND + k] * W1[k * ND + col];
            M1[(bb * 4 + row) * ND + col] = f2bf(acc);
        } else {                   // W2t rows 4*(bb-64) .. +3
            int n = (bb - 64) * 4 + row;
            W2t[n * ND + col] = f2bf(W2[col * ND + n]);
        }
        return;
    }
    for (int i = t; i < NBK; i += 1024) lcnt[i] = 0;
    __syncthreads();
    int e0 = b * TILE;
#pragma unroll
    for (int k = 0; k < TILE / 1024; k++) {
        int idx = t + k * 1024;
        int e = e0 + idx;
        if (e < NE) {
            int d = dst[e], s = src[e];
            sd[idx] = d; ss[idx] = s;
            atomicAdd(&lcnt[d >> 8], 1);
            if (mb[d] == 1) fb[s] = 1;   // benign-race byte store
        }
    }
    __syncthreads();
    for (int i = t; i < NBK; i += 1024) {
        int c = lcnt[i];
        lcnt[i] = c ? atomicAdd(&gcur[i << 4], c) : 0;
    }
    __syncthreads();
    int nv = min(NE - e0, TILE);
#pragma unroll
    for (int k = 0; k < TILE / 1024; k++) {
        int idx = t + k * 1024;
        if (idx < nv) {
            int d = sd[idx], s = ss[idx];
            int bk = d >> 8, j = d & 255;
            int pos = atomicAdd(&lcnt[bk], 1);
            if (pos < (bk + 1) * BCAP) ebuf[pos] = s | (j << 17);
        }
    }
}

// per-bucket LDS degree histogram -> carr[node]; per-node finalize (dinv/xd4,
// compaction); per-bucket allocation-weight sum -> part[b] (raw, unscanned)
__global__ void k_bhist(const int* __restrict__ gcur, const int* __restrict__ ebuf,
                        const int* __restrict__ x, const unsigned char* __restrict__ mb,
                        const unsigned char* __restrict__ fb,
                        int* __restrict__ carr, int4* __restrict__ xd4,
                        int* __restrict__ nctr, int* __restrict__ part) {
    __shared__ int bins[NPB];
    __shared__ int rs[4];
    int b = blockIdx.x, t = threadIdx.x;
    int lane = t & 63, wv = t >> 6;
    bins[t] = 0;
    __syncthreads();
    int n = min(gcur[b << 4] - b * BCAP, BCAP);
    int base = b * BCAP;
    for (int i = t; i < n; i += 256)
        atomicAdd(&bins[ebuf[base + i] >> 17], 1);
    __syncthreads();
    int node = b * NPB + t;
    int w = 0;
    if (node < NN) {
        int c = bins[t];
        carr[node] = c;
        float dv = rsqrtf((float)c + 1.0f);
        int cc = 0;
        if (fb[node] == 1) cc = atomicAdd(nctr, 1);
        xd4[node] = make_int4(x[node], __float_as_int(dv), cc, 0);
        w = c + ((mb[node] == 1) ? c : 0);   // layer-1 + co-allocated layer-2
    }
#pragma unroll
    for (int o = 32; o >= 1; o >>= 1) w += __shfl_xor(w, o, 64);
    if (lane == 0) rs[wv] = w;
    __syncthreads();
    if (t == 0) part[b] = rs[0] + rs[1] + rs[2] + rs[3];
}

// CSR placement: block base = sum(part[0..b)) (L2-hot), node offsets via LDS
// 256-scan, publish off[node] + nrec[cc], place pairs via LDS-ranked cursors
__global__ __launch_bounds__(256) void k_place(
    const int* __restrict__ gcur, const int* __restrict__ ebuf,
    const int* __restrict__ minfo, const unsigned char* __restrict__ fb,
    const int* __restrict__ carr, const int* __restrict__ part,
    const int4* __restrict__ xd4, int* __restrict__ off, int2* __restrict__ pairs,
    int4* __restrict__ nrec) {
    __shared__ int sinfo[NPB], lc1[NPB], lc2[NPB];
    __shared__ int bred[4], wtot[4];
    int b = blockIdx.x, t = threadIdx.x;
    int lane = t & 63, wv = t >> 6;
    // block base: exclusive sum of raw per-bucket weights
    int pv = 0;
    for (int i = t; i < b; i += 256) pv += part[i];
#pragma unroll
    for (int o = 32; o >= 1; o >>= 1) pv += __shfl_xor(pv, o, 64);
    if (lane == 0) bred[wv] = pv;
    __syncthreads();
    int pbase = bred[0] + bred[1] + bred[2] + bred[3];
    // per-node offsets within bucket (all 256 threads are nodes)
    int node = b * NPB + t;
    int c = 0, m = 0, f = 0;
    if (node < NN) {
        c = carr[node];
        int mv = minfo[node];
        if (mv > 0) m = mv;
        f = (fb[node] == 1) ? 1 : 0;
    }
    int wgt = c + (m ? c : 0);
    int xx = wgt;
    for (int o = 1; o < 64; o <<= 1) { int y = __shfl_up(xx, o, 64); if (lane >= o) xx += y; }
    if (lane == 63) wtot[wv] = xx;
    __syncthreads();
    int wadd = 0;
#pragma unroll
    for (int k = 0; k < 4; k++) if (k < wv) wadd += wtot[k];
    int excl = xx - wgt + wadd;
    int myoff = pbase + excl;
    if (node < NN) {
        off[node] = myoff;
        if (f) {
            int4 xv = xd4[node];
            nrec[xv.z] = make_int4(xv.x, xv.y, myoff, c);   // vocab,dinv,off,deg
        }
    }
    sinfo[t] = m | f;
    lc1[t] = myoff;
    lc2[t] = myoff + c;
    __syncthreads();
    int n = min(gcur[b << 4] - b * BCAP, BCAP);
    int base = b * BCAP;
    for (int i = t; i < n; i += 256) {
        int w = ebuf[base + i];
        int j = w >> 17, s = w & 0x1FFFF;
        int ii = sinfo[j];
        if (ii == 0) continue;
        int4 xv = xd4[s];
        if (ii & 1) {
            int p = atomicAdd(&lc1[j], 1);       // LDS atomic
            pairs[p] = make_int2(xv.x, xv.y);    // (vocab, dinv) of src
        }
        if (ii > 1) {
            int p = atomicAdd(&lc2[j], 1);       // LDS atomic
            pairs[p] = make_int2(xv.z, xv.y);    // (compact idx, dinv)
        }
    }
}

// h1c[cc] = bf16(relu(dv_i*(sum_e w_e*M1[v_e] + dv_i*M1[x_i]) + b1))
// M1 (128 KiB) staged whole into LDS; persistent 256 blocks x 16 waves,
// grid-stride over fb nodes. Per-edge gather = conflict-free ds_read_b64.
__global__ __launch_bounds__(1024) void k_expand(
    const int* __restrict__ nctr, const int4* __restrict__ nrec,
    const int2* __restrict__ pairs,
    const unsigned short* __restrict__ M1,
    const float* __restrict__ b1,
    unsigned short* __restrict__ h1c) {
    __shared__ unsigned short sm1[ND * ND];      // 128 KiB (gfx950: 160 KiB/CU)
    int t = threadIdx.x;
    {
        const uint4* g = (const uint4*)M1;       // 16B vector staging
        uint4* s = (uint4*)sm1;
        for (int i = t; i < (ND * ND) / 8; i += 1024) s[i] = g[i];
    }
    __syncthreads();
    int lane = t & 63;
    float4 b1v = ((const float4*)b1)[lane];
    int nw = nctr[0];
    for (int idx = (blockIdx.x * 1024 + t) >> 6; idx < nw; idx += 4096) {
        int4 rec = nrec[idx];
        int v0 = rec.x;
        float w0 = __int_as_float(rec.y);
        ushort4 mm = *(const ushort4*)(sm1 + v0 * ND + lane * 4);
        float a0 = w0 * bf2f(mm.x), a1 = w0 * bf2f(mm.y);
        float a2 = w0 * bf2f(mm.z), a3 = w0 * bf2f(mm.w);
        int e = rec.z, end = e + rec.w;
        for (; e + 4 <= end; e += 4) {
            int2 pA = pairs[e + 0];
            int2 pB = pairs[e + 1];
            int2 pC = pairs[e + 2];
            int2 pD = pairs[e + 3];
            ushort4 mA = *(const ushort4*)(sm1 + pA.x * ND + lane * 4);
            ushort4 mB = *(const ushort4*)(sm1 + pB.x * ND + lane * 4);
            ushort4 mC = *(const ushort4*)(sm1 + pC.x * ND + lane * 4);
            ushort4 mD = *(const ushort4*)(sm1 + pD.x * ND + lane * 4);
            float wA = __int_as_float(pA.y), wB = __int_as_float(pB.y);
            float wC = __int_as_float(pC.y), wD = __int_as_float(pD.y);
            a0 += wA * bf2f(mA.x) + wB * bf2f(mB.x) + wC * bf2f(mC.x) + wD * bf2f(mD.x);
            a1 += wA * bf2f(mA.y) + wB * bf2f(mB.y) + wC * bf2f(mC.y) + wD * bf2f(mD.y);
            a2 += wA * bf2f(mA.z) + wB * bf2f(mB.z) + wC * bf2f(mC.z) + wD * bf2f(mD.z);
            a3 += wA * bf2f(mA.w) + wB * bf2f(mB.w) + wC * bf2f(mC.w) + wD * bf2f(mD.w);
        }
        for (; e < end; e++) {
            int2 p = pairs[e];
            float w = __int_as_float(p.y);
            ushort4 m2 = *(const ushort4*)(sm1 + p.x * ND + lane * 4);
            a0 += w * bf2f(m2.x);
            a1 += w * bf2f(m2.y);
            a2 += w * bf2f(m2.z);
            a3 += w * bf2f(m2.w);
        }
        ushort4 o;
        o.x = f2bf(fmaxf(fmaf(w0, a0, b1v.x), 0.f));
        o.y = f2bf(fmaxf(fmaf(w0, a1, b1v.y), 0.f));
        o.z = f2bf(fmaxf(fmaf(w0, a2, b1v.z), 0.f));
        o.w = f2bf(fmaxf(fmaf(w0, a3, b1v.w), 0.f));
        ((ushort4*)(h1c + (size_t)idx * ND))[lane] = o;
    }
}

// layer-2 aggregation + self-loop + dv scale, bf16 out (A-matrix rows for k_out2)
// layer-2 segment of masked node p: [off[p]+c, off[p]+2c)
__global__ void k_agg2(const int* __restrict__ mpos, const int* __restrict__ minfo,
                       const int4* __restrict__ xd4,
                       const int2* __restrict__ pairs, const int* __restrict__ off,
                       const int* __restrict__ carr,
                       const unsigned short* __restrict__ h1c,
                       unsigned short* __restrict__ agg2b) {
    int lane = threadIdx.x & 63;
    int wave = (blockIdx.x * 256 + threadIdx.x) >> 6;
    if (wave >= NM) return;
    int r = wave;
    int p = mpos[r];
    if ((minfo[p] >> 1) != r + 1) return;   // duplicate mask position: not representative
    int4 xp = xd4[p];
    int cp = xp.z;
    float dv = __int_as_float(xp.y);
    ushort4 h0 = *(const ushort4*)(h1c + (size_t)cp * ND + lane * 4);
    float a0 = dv * bf2f(h0.x), a1 = dv * bf2f(h0.y);
    float a2 = dv * bf2f(h0.z), a3 = dv * bf2f(h0.w);
    int c2 = carr[p];
    int e = off[p] + c2, end = e + c2;
    for (; e + 4 <= end; e += 4) {
        int2 pA = pairs[e + 0];
        int2 pB = pairs[e + 1];
        int2 pC = pairs[e + 2];
        int2 pD = pairs[e + 3];
        ushort4 hA = *(const ushort4*)(h1c + (size_t)pA.x * ND + lane * 4);
        ushort4 hB = *(const ushort4*)(h1c + (size_t)pB.x * ND + lane * 4);
        ushort4 hC = *(const ushort4*)(h1c + (size_t)pC.x * ND + lane * 4);
        ushort4 hD = *(const ushort4*)(h1c + (size_t)pD.x * ND + lane * 4);
        float wA = __int_as_float(pA.y), wB = __int_as_float(pB.y);
        float wC = __int_as_float(pC.y), wD = __int_as_float(pD.y);
        a0 += wA * bf2f(hA.x) + wB * bf2f(hB.x) + wC * bf2f(hC.x) + wD * bf2f(hD.x);
        a1 += wA * bf2f(hA.y) + wB * bf2f(hB.y) + wC * bf2f(hC.y) + wD * bf2f(hD.y);
        a2 += wA * bf2f(hA.z) + wB * bf2f(hB.z) + wC * bf2f(hC.z) + wD * bf2f(hD.z);
        a3 += wA * bf2f(hA.w) + wB * bf2f(hB.w) + wC * bf2f(hC.w) + wD * bf2f(hD.w);
    }
    for (; e < end; e++) {
        int2 pp = pairs[e];
        float w = __int_as_float(pp.y);
        ushort4 hv = *(const ushort4*)(h1c + (size_t)pp.x * ND + lane * 4);
        a0 += w * bf2f(hv.x);
        a1 += w * bf2f(hv.y);
        a2 += w * bf2f(hv.z);
        a3 += w * bf2f(hv.w);
    }
    ushort4 o;
    o.x = f2bf(dv * a0);
    o.y = f2bf(dv * a1);
    o.z = f2bf(dv * a2);
    o.w = f2bf(dv * a3);
    ((ushort4*)(agg2b + (size_t)r * ND))[lane] = o;
}

// MFMA GEMM + log-softmax: out[j] = log_softmax(agg2b[rep(j)] @ W2 + b2)
__global__ __launch_bounds__(256) void k_out2(
    const int* __restrict__ mpos, const int* __restrict__ minfo,
    const unsigned short* __restrict__ agg2b, const unsigned short* __restrict__ W2t,
    const float* __restrict__ b2, float* __restrict__ out) {
    int lane = threadIdx.x & 63;
    int wv = threadIdx.x >> 6;
    int row0 = blockIdx.x * 64 + wv * 16;   // 16 rows per wave
    int qm = lane & 15, qk = lane >> 4;
    int row = row0 + qm;
    bf16x8 afr[8];
    if (row < NM) {
        int p = mpos[row];
        int rr = (minfo[p] >> 1) - 1;
        const unsigned short* arow = agg2b + (size_t)rr * ND + qk * 8;
#pragma unroll
        for (int kt = 0; kt < 8; kt++) afr[kt] = *(const bf16x8*)(arow + kt * 32);
    } else {
#pragma unroll
        for (int kt = 0; kt < 8; kt++) afr[kt] = (bf16x8){0, 0, 0, 0, 0, 0, 0, 0};
    }
    f32x4 acc[16];
#pragma unroll
    for (int t = 0; t < 16; t++) acc[t] = (f32x4){0.f, 0.f, 0.f, 0.f};
#pragma unroll
    for (int t = 0; t < 16; t++) {
        const unsigned short* brow = W2t + (size_t)(t * 16 + qm) * ND + qk * 8;
#pragma unroll
        for (int kt = 0; kt < 8; kt++) {
            bf16x8 bfr = *(const bf16x8*)(brow + kt * 32);
            acc[t] = __builtin_amdgcn_mfma_f32_16x16x32_bf16(afr[kt], bfr, acc[t], 0, 0, 0);
        }
    }
    float mx[4] = {-1e30f, -1e30f, -1e30f, -1e30f};
#pragma unroll
    for (int t = 0; t < 16; t++) {
        float cb = b2[qm + 16 * t];
#pragma unroll
        for (int r = 0; r < 4; r++) {
            float v = acc[t][r] + cb;
            acc[t][r] = v;
            mx[r] = fmaxf(mx[r], v);
        }
    }
#pragma unroll
    for (int r = 0; r < 4; r++)
        for (int o = 1; o < 16; o <<= 1) mx[r] = fmaxf(mx[r], __shfl_xor(mx[r], o, 64));
    float sm[4] = {0.f, 0.f, 0.f, 0.f};
#pragma unroll
    for (int t = 0; t < 16; t++)
#pragma unroll
        for (int r = 0; r < 4; r++) sm[r] += __expf(acc[t][r] - mx[r]);
#pragma unroll
    for (int r = 0; r < 4; r++)
        for (int o = 1; o < 16; o <<= 1) sm[r] += __shfl_xor(sm[r], o, 64);
#pragma unroll
    for (int r = 0; r < 4; r++) {
        int orow_i = row0 + qk * 4 + r;
        if (orow_i >= NM) continue;
        float lse = mx[r] + __logf(sm[r]);
        float* orow = out + (size_t)orow_i * ND + qm;
#pragma unroll
        for (int t = 0; t < 16; t++) orow[16 * t] = acc[t][r] - lse;
    }
}

extern "C" void kernel_launch(void* const* d_in, const int* in_sizes, int n_in,
                              void* d_out, int out_size, void* d_ws, size_t ws_size,
                              hipStream_t stream) {
    const int* x    = (const int*)d_in[0];
    const int* ei   = (const int*)d_in[1];
    const int* src  = ei;
    const int* dst  = ei + NE;
    const int* mpos = (const int*)d_in[2];
    const float* emb = (const float*)d_in[3];
    const float* W1  = (const float*)d_in[4];
    const float* b1  = (const float*)d_in[5];
    const float* W2  = (const float*)d_in[6];
    const float* b2  = (const float*)d_in[7];
    float* out = (float*)d_out;

    char* w = (char*)d_ws;
    size_t o = 0;
#define ALLOC(nbytes) ({ void* _p = (void*)(w + o); o = (o + (size_t)(nbytes) + 63) & ~(size_t)63; _p; })
    int*   carr  = (int*)ALLOC((size_t)(NN + 64) * 4);
    int*   off   = (int*)ALLOC((size_t)(NN + 64) * 4);
    int*   minfo = (int*)ALLOC((size_t)NN * 4);
    unsigned char* mb = (unsigned char*)ALLOC(NN + 64);
    unsigned char* fb = (unsigned char*)ALLOC(NN + 64);
    int4*  xd4   = (int4*)ALLOC((size_t)NN * 16);                        // 1.6 MB
    int*   nctr  = (int*)ALLOC(64);
    int*   part  = (int*)ALLOC(512 * 4);                                 // NBK partials
    int*   gcur  = (int*)ALLOC((size_t)(NBK * 16 + 64) * 4);             // 1 line/counter
    int*   ebuf  = (int*)ALLOC((size_t)NBK * BCAP * 4);                  // 4.0 MB
    unsigned short* M1    = (unsigned short*)ALLOC((size_t)ND * ND * 2);
    unsigned short* W2t   = (unsigned short*)ALLOC((size_t)ND * ND * 2);
    unsigned short* agg2b = (unsigned short*)ALLOC((size_t)NM * ND * 2); // 5.1 MB
    int2*  pairs = (int2*)ALLOC((size_t)NE * 2 * 8);                     // 12.8 MB
    int4*  nrec  = (int4*)ALLOC((size_t)NN * 16);                        // 1.6 MB
    unsigned short* h1c  = (unsigned short*)ALLOC((size_t)NN * ND * 2);  // 51.2 MB
#undef ALLOC

    k_maskmap<<<(NM + 255) / 256, 256, 0, stream>>>(mpos, minfo, mb, fb, gcur, nctr);
    k_bin<<<EBK + 128, 1024, 0, stream>>>(src, dst, mb, fb, gcur, ebuf,
                                          emb, W1, W2, M1, W2t);
    k_bhist<<<NBK, 256, 0, stream>>>(gcur, ebuf, x, mb, fb, carr, xd4, nctr, part);
    k_place<<<NBK, 256, 0, stream>>>(gcur, ebuf, minfo, fb, carr, part, xd4, off, pairs, nrec);
    k_expand<<<256, 1024, 0, stream>>>(nctr, nrec, pairs, M1, b1, h1c);
    k_agg2<<<(NM + 3) / 4, 256, 0, stream>>>(mpos, minfo, xd4, pairs, off, carr, h1c, agg2b);
    k_out2<<<NMP / 64, 256, 0, stream>>>(mpos, minfo, agg2b, W2t, b2, out);
}

// Round 12
// 188.095 us; speedup vs baseline: 1.1464x; 1.0125x over previous
//
#include <hip/hip_runtime.h>
#include <stdint.h>

#define NN 100000            // nodes
#define NE 800000            // edges
#define ND 256               // dim (vocab = node_dim = hidden = 256)
#define NM 10000             // masked outputs
#define NMP 10048            // NM padded to 64-row blocks
#define NPB 256              // nodes per bucket
#define NBK 391              // buckets = ceil(NN/NPB)
#define BCAP 2560            // bucket capacity (mean 2048, +11 sigma)
#define TILE 4096            // edges per k_bin block
#define EBK ((NE + TILE - 1) / TILE) // 196 edge blocks

typedef __attribute__((ext_vector_type(8))) short bf16x8;
typedef __attribute__((ext_vector_type(4))) float f32x4;

__device__ __forceinline__ float bf2f(unsigned short u) {
    return __uint_as_float(((unsigned)u) << 16);
}
__device__ __forceinline__ unsigned short f2bf(float f) {
    unsigned u = __float_as_uint(f);
    u += 0x7fffu + ((u >> 16) & 1u);   // RNE
    return (unsigned short)(u >> 16);
}

// Round-11 structure (reproduced 189.7-190.6us) with ONE change: k_bin
// bucket-sorts each tile in LDS and writes ebuf in slot order. Rationale:
// k_bin counters show WRITE 33MB vs 3.2MB payload (10x write-allocate,
// isolated 4B stores). Sorted copy -> runs of ~10.5 entries/bucket ->
// ~10x fewer write transactions. Payload/protocol byte-identical.
// Poison-typed maps (d_ws poisoned 0xAA; no zero-init anywhere):
//   mb[i]==1 masked; fb[i]==1 h1 needed; minfo[i]>0 masked, (>>1)-1 = row.
// Layer-2 co-allocation: node p owns [off[p],off[p]+c) L1, [off+c,off+2c) L2.
// nrec[cc] = (vocab, dinv, off, deg) -- k_expand worklist (compact h1c index).

__global__ void k_maskmap(const int* __restrict__ mpos, int* __restrict__ minfo,
                          unsigned char* __restrict__ mb, unsigned char* __restrict__ fb,
                          int* __restrict__ gcur, int* __restrict__ nctr) {
    int j = blockIdx.x * 256 + threadIdx.x;
    if (j < NM) {
        int p = mpos[j];
        minfo[p] = (j + 1) << 1;   // duplicates: any winner
        mb[p] = 1;
        fb[p] = 1;                 // masked pos needs h1 (self-loop)
    }
    if (j < NBK) gcur[j << 4] = j * BCAP;   // padded: 1 line per counter
    if (j == 0) *nctr = 0;
}

// LDS bucket-sorted binning (blocks < EBK, 1024 thr) +
// M1 build (next 64 blocks, 4 rows each) + W2t build (next 64 blocks)
__global__ __launch_bounds__(1024) void k_bin(
    const int* __restrict__ src, const int* __restrict__ dst,
    const unsigned char* __restrict__ mb, unsigned char* __restrict__ fb,
    int* __restrict__ gcur, int* __restrict__ ebuf,
    const float* __restrict__ emb, const float* __restrict__ W1,
    const float* __restrict__ W2,
    unsigned short* __restrict__ M1, unsigned short* __restrict__ W2t) {
    __shared__ int lcnt[NBK], lstart[NBK], delta[NBK], cur[NBK];
    __shared__ int sv[TILE], sgd[TILE];
    __shared__ int wsum[8], wpre[8];
    __shared__ float er4[4 * ND];
    int b = blockIdx.x, t = threadIdx.x;
    int lane = t & 63, wv = t >> 6;
    if (b >= EBK) {
        int bb = b - EBK;          // 0..127
        int row = t >> 8, col = t & 255;
        if (bb < 64) {             // M1 rows 4*bb .. 4*bb+3
            er4[t] = emb[(bb * 4) * ND + t];
            __syncthreads();
            float acc = 0.f;
            for (int k = 0; k < ND; k++) acc += er4[row * ND + k] * W1[k * ND + col];
            M1[(bb * 4 + row) * ND + col] = f2bf(acc);
        } else {                   // W2t rows 4*(bb-64) .. +3
            int n = (bb - 64) * 4 + row;
            W2t[n * ND + col] = f2bf(W2[col * ND + n]);
        }
        return;
    }
    for (int i = t; i < NBK; i += 1024) lcnt[i] = 0;
    __syncthreads();
    int e0 = b * TILE;
    int nv = min(NE - e0, TILE);
    // phase 1: per-bucket counts + mask propagation
#pragma unroll
    for (int k = 0; k < TILE / 1024; k++) {
        int e = e0 + t + k * 1024;
        if (e < NE) {
            int d = dst[e];
            atomicAdd(&lcnt[d >> 8], 1);
            if (mb[d] == 1) fb[src[e]] = 1;   // benign-race byte store
        }
    }
    __syncthreads();
    // phase 2: exclusive scan of lcnt (7 waves cover 448 >= NBK) +
    // per-bucket gcur reservation; delta[bk] = gpos - lstart
    {
        int v = 0;
        if (t < 448) {
            v = (t < NBK) ? lcnt[t] : 0;
            int incl = v;
            for (int o = 1; o < 64; o <<= 1) {
                int y = __shfl_up(incl, o, 64);
                if (lane >= o) incl += y;
            }
            if (lane == 63) wsum[wv] = incl;
            if (t < NBK) lstart[t] = incl - v;    // intra-wave exclusive
        }
        __syncthreads();
        if (t == 0) {
            int s = 0;
            for (int k = 0; k < 7; k++) { wpre[k] = s; s += wsum[k]; }
        }
        __syncthreads();
        if (t < NBK) {
            int ls = lstart[t] + wpre[wv];
            lstart[t] = ls;
            int c = v;
            int gpos = c ? atomicAdd(&gcur[t << 4], c) : 0;
            delta[t] = gpos - ls;
            cur[t] = ls;
        }
    }
    __syncthreads();
    // phase 3: scatter edges into LDS in bucket-sorted slots
#pragma unroll
    for (int k = 0; k < TILE / 1024; k++) {
        int e = e0 + t + k * 1024;
        if (e < NE) {
            int d = dst[e], s = src[e];
            int bk = d >> 8;
            int r = atomicAdd(&cur[bk], 1);
            int gp = delta[bk] + r;
            sv[r] = s | ((d & 255) << 17);
            sgd[r] = (gp < (bk + 1) * BCAP) ? gp : -1;   // capacity guard
        }
    }
    __syncthreads();
    // phase 4: ordered copy LDS -> ebuf (runs of ~TILE/NBK per bucket)
    for (int i = t; i < nv; i += 1024) {
        int gp = sgd[i];
        if (gp >= 0) ebuf[gp] = sv[i];
    }
}

// per-bucket LDS degree histogram -> carr[node]; per-node finalize (dinv/xd4,
// compaction); per-bucket allocation-weight sum -> part[b] (raw, unscanned)
__global__ void k_bhist(const int* __restrict__ gcur, const int* __restrict__ ebuf,
                        const int* __restrict__ x, const unsigned char* __restrict__ mb,
                        const unsigned char* __restrict__ fb,
                        int* __restrict__ carr, int4* __restrict__ xd4,
                        int* __restrict__ nctr, int* __restrict__ part) {
    __shared__ int bins[NPB];
    __shared__ int rs[4];
    int b = blockIdx.x, t = threadIdx.x;
    int lane = t & 63, wv = t >> 6;
    bins[t] = 0;
    __syncthreads();
    int n = min(gcur[b << 4] - b * BCAP, BCAP);
    int base = b * BCAP;
    for (int i = t; i < n; i += 256)
        atomicAdd(&bins[ebuf[base + i] >> 17], 1);
    __syncthreads();
    int node = b * NPB + t;
    int w = 0;
    if (node < NN) {
        int c = bins[t];
        carr[node] = c;
        float dv = rsqrtf((float)c + 1.0f);
        int cc = 0;
        if (fb[node] == 1) cc = atomicAdd(nctr, 1);
        xd4[node] = make_int4(x[node], __float_as_int(dv), cc, 0);
        w = c + ((mb[node] == 1) ? c : 0);   // layer-1 + co-allocated layer-2
    }
#pragma unroll
    for (int o = 32; o >= 1; o >>= 1) w += __shfl_xor(w, o, 64);
    if (lane == 0) rs[wv] = w;
    __syncthreads();
    if (t == 0) part[b] = rs[0] + rs[1] + rs[2] + rs[3];
}

// CSR placement: block base = sum(part[0..b)) (L2-hot), node offsets via LDS
// 256-scan, publish off[node] + nrec[cc], place pairs via LDS-ranked cursors
__global__ __launch_bounds__(256) void k_place(
    const int* __restrict__ gcur, const int* __restrict__ ebuf,
    const int* __restrict__ minfo, const unsigned char* __restrict__ fb,
    const int* __restrict__ carr, const int* __restrict__ part,
    const int4* __restrict__ xd4, int* __restrict__ off, int2* __restrict__ pairs,
    int4* __restrict__ nrec) {
    __shared__ int sinfo[NPB], lc1[NPB], lc2[NPB];
    __shared__ int bred[4], wtot[4];
    int b = blockIdx.x, t = threadIdx.x;
    int lane = t & 63, wv = t >> 6;
    // block base: exclusive sum of raw per-bucket weights
    int pv = 0;
    for (int i = t; i < b; i += 256) pv += part[i];
#pragma unroll
    for (int o = 32; o >= 1; o >>= 1) pv += __shfl_xor(pv, o, 64);
    if (lane == 0) bred[wv] = pv;
    __syncthreads();
    int pbase = bred[0] + bred[1] + bred[2] + bred[3];
    // per-node offsets within bucket (all 256 threads are nodes)
    int node = b * NPB + t;
    int c = 0, m = 0, f = 0;
    if (node < NN) {
        c = carr[node];
        int mv = minfo[node];
        if (mv > 0) m = mv;
        f = (fb[node] == 1) ? 1 : 0;
    }
    int wgt = c + (m ? c : 0);
    int xx = wgt;
    for (int o = 1; o < 64; o <<= 1) { int y = __shfl_up(xx, o, 64); if (lane >= o) xx += y; }
    if (lane == 63) wtot[wv] = xx;
    __syncthreads();
    int wadd = 0;
#pragma unroll
    for (int k = 0; k < 4; k++) if (k < wv) wadd += wtot[k];
    int excl = xx - wgt + wadd;
    int myoff = pbase + excl;
    if (node < NN) {
        off[node] = myoff;
        if (f) {
            int4 xv = xd4[node];
            nrec[xv.z] = make_int4(xv.x, xv.y, myoff, c);   // vocab,dinv,off,deg
        }
    }
    sinfo[t] = m | f;
    lc1[t] = myoff;
    lc2[t] = myoff + c;
    __syncthreads();
    int n = min(gcur[b << 4] - b * BCAP, BCAP);
    int base = b * BCAP;
    for (int i = t; i < n; i += 256) {
        int w = ebuf[base + i];
        int j = w >> 17, s = w & 0x1FFFF;
        int ii = sinfo[j];
        if (ii == 0) continue;
        int4 xv = xd4[s];
        if (ii & 1) {
            int p = atomicAdd(&lc1[j], 1);       // LDS atomic
            pairs[p] = make_int2(xv.x, xv.y);    // (vocab, dinv) of src
        }
        if (ii > 1) {
            int p = atomicAdd(&lc2[j], 1);       // LDS atomic
            pairs[p] = make_int2(xv.z, xv.y);    // (compact idx, dinv)
        }
    }
}

// h1c[cc] = bf16(relu(dv_i*(sum_e w_e*M1[v_e] + dv_i*M1[x_i]) + b1))
// M1 (128 KiB) staged whole into LDS; persistent 256 blocks x 16 waves,
// grid-stride over fb nodes. Per-edge gather = conflict-free ds_read_b64.
__global__ __launch_bounds__(1024) void k_expand(
    const int* __restrict__ nctr, const int4* __restrict__ nrec,
    const int2* __restrict__ pairs,
    const unsigned short* __restrict__ M1,
    const float* __restrict__ b1,
    unsigned short* __restrict__ h1c) {
    __shared__ unsigned short sm1[ND * ND];      // 128 KiB (gfx950: 160 KiB/CU)
    int t = threadIdx.x;
    {
        const uint4* g = (const uint4*)M1;       // 16B vector staging
        uint4* s = (uint4*)sm1;
        for (int i = t; i < (ND * ND) / 8; i += 1024) s[i] = g[i];
    }
    __syncthreads();
    int lane = t & 63;
    float4 b1v = ((const float4*)b1)[lane];
    int nw = nctr[0];
    for (int idx = (blockIdx.x * 1024 + t) >> 6; idx < nw; idx += 4096) {
        int4 rec = nrec[idx];
        int v0 = rec.x;
        float w0 = __int_as_float(rec.y);
        ushort4 mm = *(const ushort4*)(sm1 + v0 * ND + lane * 4);
        float a0 = w0 * bf2f(mm.x), a1 = w0 * bf2f(mm.y);
        float a2 = w0 * bf2f(mm.z), a3 = w0 * bf2f(mm.w);
        int e = rec.z, end = e + rec.w;
        for (; e + 4 <= end; e += 4) {
            int2 pA = pairs[e + 0];
            int2 pB = pairs[e + 1];
            int2 pC = pairs[e + 2];
            int2 pD = pairs[e + 3];
            ushort4 mA = *(const ushort4*)(sm1 + pA.x * ND + lane * 4);
            ushort4 mB = *(const ushort4*)(sm1 + pB.x * ND + lane * 4);
            ushort4 mC = *(const ushort4*)(sm1 + pC.x * ND + lane * 4);
            ushort4 mD = *(const ushort4*)(sm1 + pD.x * ND + lane * 4);
            float wA = __int_as_float(pA.y), wB = __int_as_float(pB.y);
            float wC = __int_as_float(pC.y), wD = __int_as_float(pD.y);
            a0 += wA * bf2f(mA.x) + wB * bf2f(mB.x) + wC * bf2f(mC.x) + wD * bf2f(mD.x);
            a1 += wA * bf2f(mA.y) + wB * bf2f(mB.y) + wC * bf2f(mC.y) + wD * bf2f(mD.y);
            a2 += wA * bf2f(mA.z) + wB * bf2f(mB.z) + wC * bf2f(mC.z) + wD * bf2f(mD.z);
            a3 += wA * bf2f(mA.w) + wB * bf2f(mB.w) + wC * bf2f(mC.w) + wD * bf2f(mD.w);
        }
        for (; e < end; e++) {
            int2 p = pairs[e];
            float w = __int_as_float(p.y);
            ushort4 m2 = *(const ushort4*)(sm1 + p.x * ND + lane * 4);
            a0 += w * bf2f(m2.x);
            a1 += w * bf2f(m2.y);
            a2 += w * bf2f(m2.z);
            a3 += w * bf2f(m2.w);
        }
        ushort4 o;
        o.x = f2bf(fmaxf(fmaf(w0, a0, b1v.x), 0.f));
        o.y = f2bf(fmaxf(fmaf(w0, a1, b1v.y), 0.f));
        o.z = f2bf(fmaxf(fmaf(w0, a2, b1v.z), 0.f));
        o.w = f2bf(fmaxf(fmaf(w0, a3, b1v.w), 0.f));
        ((ushort4*)(h1c + (size_t)idx * ND))[lane] = o;
    }
}

// layer-2 aggregation + self-loop + dv scale, bf16 out (A-matrix rows for k_out2)
// layer-2 segment of masked node p: [off[p]+c, off[p]+2c)
__global__ void k_agg2(const int* __restrict__ mpos, const int* __restrict__ minfo,
                       const int4* __restrict__ xd4,
                       const int2* __restrict__ pairs, const int* __restrict__ off,
                       const int* __restrict__ carr,
                       const unsigned short* __restrict__ h1c,
                       unsigned short* __restrict__ agg2b) {
    int lane = threadIdx.x & 63;
    int wave = (blockIdx.x * 256 + threadIdx.x) >> 6;
    if (wave >= NM) return;
    int r = wave;
    int p = mpos[r];
    if ((minfo[p] >> 1) != r + 1) return;   // duplicate mask position: not representative
    int4 xp = xd4[p];
    int cp = xp.z;
    float dv = __int_as_float(xp.y);
    ushort4 h0 = *(const ushort4*)(h1c + (size_t)cp * ND + lane * 4);
    float a0 = dv * bf2f(h0.x), a1 = dv * bf2f(h0.y);
    float a2 = dv * bf2f(h0.z), a3 = dv * bf2f(h0.w);
    int c2 = carr[p];
    int e = off[p] + c2, end = e + c2;
    for (; e + 4 <= end; e += 4) {
        int2 pA = pairs[e + 0];
        int2 pB = pairs[e + 1];
        int2 pC = pairs[e + 2];
        int2 pD = pairs[e + 3];
        ushort4 hA = *(const ushort4*)(h1c + (size_t)pA.x * ND + lane * 4);
        ushort4 hB = *(const ushort4*)(h1c + (size_t)pB.x * ND + lane * 4);
        ushort4 hC = *(const ushort4*)(h1c + (size_t)pC.x * ND + lane * 4);
        ushort4 hD = *(const ushort4*)(h1c + (size_t)pD.x * ND + lane * 4);
        float wA = __int_as_float(pA.y), wB = __int_as_float(pB.y);
        float wC = __int_as_float(pC.y), wD = __int_as_float(pD.y);
        a0 += wA * bf2f(hA.x) + wB * bf2f(hB.x) + wC * bf2f(hC.x) + wD * bf2f(hD.x);
        a1 += wA * bf2f(hA.y) + wB * bf2f(hB.y) + wC * bf2f(hC.y) + wD * bf2f(hD.y);
        a2 += wA * bf2f(hA.z) + wB * bf2f(hB.z) + wC * bf2f(hC.z) + wD * bf2f(hD.z);
        a3 += wA * bf2f(hA.w) + wB * bf2f(hB.w) + wC * bf2f(hC.w) + wD * bf2f(hD.w);
    }
    for (; e < end; e++) {
        int2 pp = pairs[e];
        float w = __int_as_float(pp.y);
        ushort4 hv = *(const ushort4*)(h1c + (size_t)pp.x * ND + lane * 4);
        a0 += w * bf2f(hv.x);
        a1 += w * bf2f(hv.y);
        a2 += w * bf2f(hv.z);
        a3 += w * bf2f(hv.w);
    }
    ushort4 o;
    o.x = f2bf(dv * a0);
    o.y = f2bf(dv * a1);
    o.z = f2bf(dv * a2);
    o.w = f2bf(dv * a3);
    ((ushort4*)(agg2b + (size_t)r * ND))[lane] = o;
}

// MFMA GEMM + log-softmax: out[j] = log_softmax(agg2b[rep(j)] @ W2 + b2)
__global__ __launch_bounds__(256) void k_out2(
    const int* __restrict__ mpos, const int* __restrict__ minfo,
    const unsigned short* __restrict__ agg2b, const unsigned short* __restrict__ W2t,
    const float* __restrict__ b2, float* __restrict__ out) {
    int lane = threadIdx.x & 63;
    int wv = threadIdx.x >> 6;
    int row0 = blockIdx.x * 64 + wv * 16;   // 16 rows per wave
    int qm = lane & 15, qk = lane >> 4;
    int row = row0 + qm;
    bf16x8 afr[8];
    if (row < NM) {
        int p = mpos[row];
        int rr = (minfo[p] >> 1) - 1;
        const unsigned short* arow = agg2b + (size_t)rr * ND + qk * 8;
#pragma unroll
        for (int kt = 0; kt < 8; kt++) afr[kt] = *(const bf16x8*)(arow + kt * 32);
    } else {
#pragma unroll
        for (int kt = 0; kt < 8; kt++) afr[kt] = (bf16x8){0, 0, 0, 0, 0, 0, 0, 0};
    }
    f32x4 acc[16];
#pragma unroll
    for (int t = 0; t < 16; t++) acc[t] = (f32x4){0.f, 0.f, 0.f, 0.f};
#pragma unroll
    for (int t = 0; t < 16; t++) {
        const unsigned short* brow = W2t + (size_t)(t * 16 + qm) * ND + qk * 8;
#pragma unroll
        for (int kt = 0; kt < 8; kt++) {
            bf16x8 bfr = *(const bf16x8*)(brow + kt * 32);
            acc[t] = __builtin_amdgcn_mfma_f32_16x16x32_bf16(afr[kt], bfr, acc[t], 0, 0, 0);
        }
    }
    float mx[4] = {-1e30f, -1e30f, -1e30f, -1e30f};
#pragma unroll
    for (int t = 0; t < 16; t++) {
        float cb = b2[qm + 16 * t];
#pragma unroll
        for (int r = 0; r < 4; r++) {
            float v = acc[t][r] + cb;
            acc[t][r] = v;
            mx[r] = fmaxf(mx[r], v);
        }
    }
#pragma unroll
    for (int r = 0; r < 4; r++)
        for (int o = 1; o < 16; o <<= 1) mx[r] = fmaxf(mx[r], __shfl_xor(mx[r], o, 64));
    float sm[4] = {0.f, 0.f, 0.f, 0.f};
#pragma unroll
    for (int t = 0; t < 16; t++)
#pragma unroll
        for (int r = 0; r < 4; r++) sm[r] += __expf(acc[t][r] - mx[r]);
#pragma unroll
    for (int r = 0; r < 4; r++)
        for (int o = 1; o < 16; o <<= 1) sm[r] += __shfl_xor(sm[r], o, 64);
#pragma unroll
    for (int r = 0; r < 4; r++) {
        int orow_i = row0 + qk * 4 + r;
        if (orow_i >= NM) continue;
        float lse = mx[r] + __logf(sm[r]);
        float* orow = out + (size_t)orow_i * ND + qm;
#pragma unroll
        for (int t = 0; t < 16; t++) orow[16 * t] = acc[t][r] - lse;
    }
}

extern "C" void kernel_launch(void* const* d_in, const int* in_sizes, int n_in,
                              void* d_out, int out_size, void* d_ws, size_t ws_size,
                              hipStream_t stream) {
    const int* x    = (const int*)d_in[0];
    const int* ei   = (const int*)d_in[1];
    const int* src  = ei;
    const int* dst  = ei + NE;
    const int* mpos = (const int*)d_in[2];
    const float* emb = (const float*)d_in[3];
    const float* W1  = (const float*)d_in[4];
    const float* b1  = (const float*)d_in[5];
    const float* W2  = (const float*)d_in[6];
    const float* b2  = (const float*)d_in[7];
    float* out = (float*)d_out;

    char* w = (char*)d_ws;
    size_t o = 0;
#define ALLOC(nbytes) ({ void* _p = (void*)(w + o); o = (o + (size_t)(nbytes) + 63) & ~(size_t)63; _p; })
    int*   carr  = (int*)ALLOC((size_t)(NN + 64) * 4);
    int*   off   = (int*)ALLOC((size_t)(NN + 64) * 4);
    int*   minfo = (int*)ALLOC((size_t)NN * 4);
    unsigned char* mb = (unsigned char*)ALLOC(NN + 64);
    unsigned char* fb = (unsigned char*)ALLOC(NN + 64);
    int4*  xd4   = (int4*)ALLOC((size_t)NN * 16);                        // 1.6 MB
    int*   nctr  = (int*)ALLOC(64);
    int*   part  = (int*)ALLOC(512 * 4);                                 // NBK partials
    int*   gcur  = (int*)ALLOC((size_t)(NBK * 16 + 64) * 4);             // 1 line/counter
    int*   ebuf  = (int*)ALLOC((size_t)NBK * BCAP * 4);                  // 4.0 MB
    unsigned short* M1    = (unsigned short*)ALLOC((size_t)ND * ND * 2);
    unsigned short* W2t   = (unsigned short*)ALLOC((size_t)ND * ND * 2);
    unsigned short* agg2b = (unsigned short*)ALLOC((size_t)NM * ND * 2); // 5.1 MB
    int2*  pairs = (int2*)ALLOC((size_t)NE * 2 * 8);                     // 12.8 MB
    int4*  nrec  = (int4*)ALLOC((size_t)NN * 16);                        // 1.6 MB
    unsigned short* h1c  = (unsigned short*)ALLOC((size_t)NN * ND * 2);  // 51.2 MB
#undef ALLOC

    k_maskmap<<<(NM + 255) / 256, 256, 0, stream>>>(mpos, minfo, mb, fb, gcur, nctr);
    k_bin<<<EBK + 128, 1024, 0, stream>>>(src, dst, mb, fb, gcur, ebuf,
                                          emb, W1, W2, M1, W2t);
    k_bhist<<<NBK, 256, 0, stream>>>(gcur, ebuf, x, mb, fb, carr, xd4, nctr, part);
    k_place<<<NBK, 256, 0, stream>>>(gcur, ebuf, minfo, fb, carr, part, xd4, off, pairs, nrec);
    k_expand<<<256, 1024, 0, stream>>>(nctr, nrec, pairs, M1, b1, h1c);
    k_agg2<<<(NM + 3) / 4, 256, 0, stream>>>(mpos, minfo, xd4, pairs, off, carr, h1c, agg2b);
    k_out2<<<NMP / 64, 256, 0, stream>>>(mpos, minfo, agg2b, W2t, b2, out);
}